// Round 5
// baseline (208.304 us; speedup 1.0000x reference)
//
#include <hip/hip_runtime.h>

#define NTOK 8192
#define DDIM 1024
#define NEXP 16
#define NPAIR 136   // E*(E+1)/2 pairs with e<=f
#define XROW 1032   // LDS x-tile row stride in floats (pad 8: 2-way alias only)
#define NBLK 1024   // fused grid size
#define NGRP 64     // reduction groups (16 CONTIGUOUS blocks each)
#define GSZ  16

// ws layout (floats): gwT4 [16384] | slots [1024*1024] | G [136 (+pad 256)] | counters (65 ints)
#define WS_GWT  0
#define WS_SLOT 16384
#define WS_G    (WS_SLOT + NBLK * DDIM)          // 1064960
#define WS_CNT  (WS_G + 256)                     // int index: [0..63] grp, [64] fin

// ---------------------------------------------------------------------------
// Prep: transpose gate_w [16][1024] -> gwT4[d4][e]; zero G + counters.
// ---------------------------------------------------------------------------
__global__ __launch_bounds__(256) void moe_prep(
    const float* __restrict__ gate_w,
    float* __restrict__ ws)
{
    const int gid = blockIdx.x * 256 + threadIdx.x;   // 0..4095
    const int e = gid & 15;
    const int d4 = gid >> 4;                          // 0..255
    const float4* gw4 = (const float4*)gate_w;
    float4* gwT4 = (float4*)(ws + WS_GWT);
    gwT4[d4 * 16 + e] = gw4[e * 256 + d4];
    if (gid < 256) (ws + WS_G)[gid] = 0.f;
    if (gid < NGRP + 1) ((int*)ws)[WS_CNT + gid] = 0;
}

// ---------------------------------------------------------------------------
// Fused: 1024 blocks x 256 thr, 8 tokens/block.
// A: x-tile -> LDS; thread t owns d-cols 4t..4t+3 -> x^2 partials in regs.
// B: routing (LDS x broadcast + gwT coalesced). C: top2 shfl scan.
// D: combine, coalesced float4 out.
// E1: x^2 partial -> private slot (agent-scope plain stores), group ticket.
// E2: 16th arriver of each CONTIGUOUS group reduces its 64 KB slot span,
//     then computes the group's PARTIAL GRAM (Gram is linear in s):
//     G_g[p] = sum_d sg[d]*re[pe,d]*re[pf,d], 136 pair-threads, sg in LDS,
//     re rows L2-hot, unroll-8 ILP; 64 reducers run on 64 CUs in parallel
//     and each starts as soon as ITS OWN group finishes (overlaps stragglers).
//     Then 136 atomicAdds into G + fin ticket.
// E3: 64th finisher: norms from G diagonal, clipped cosine mean (~1 us).
// (R4 post-mortem: single-block latency-bound tail was ~38 us; this spreads
//  it across 64 CUs and kills the serial Gram.)
// ---------------------------------------------------------------------------
__global__ __launch_bounds__(256, 4) void moe_fused(
    const float* __restrict__ x,
    const float* __restrict__ gate_b,
    const float* __restrict__ sh,
    const float* __restrict__ re,
    float* __restrict__ out,
    float* __restrict__ ws)
{
    __shared__ __align__(16) float xt[8][XROW];
    __shared__ float nr[NEXP];
    __shared__ float lsum;
    __shared__ int   role;

    const int t = threadIdx.x;
    const int b = blockIdx.x;
    const float4* gwT4 = (const float4*)(ws + WS_GWT);
    int* cnt = (int*)ws + WS_CNT;

    // ---- A: stage 8 token rows, accumulate x^2 for owned d-columns ----
    float4 ss = make_float4(0.f, 0.f, 0.f, 0.f);
    {
        const float4* x4 = (const float4*)x + (size_t)b * 2048;
        #pragma unroll
        for (int i = 0; i < 8; ++i) {
            float4 v = x4[i * 256 + t];
            *(float4*)&xt[i][4 * t] = v;
            ss.x = fmaf(v.x, v.x, ss.x);
            ss.y = fmaf(v.y, v.y, ss.y);
            ss.z = fmaf(v.z, v.z, ss.z);
            ss.w = fmaf(v.w, v.w, ss.w);
        }
    }
    __syncthreads();

    const int lane = t & 63;
    const int wave = t >> 6;
    const int e = lane & 15;
    const int h = (lane >> 4) & 1;
    const int g = lane >> 5;

    // ---- B: routing ----
    const int tokL = wave * 2 + g;
    const float* xrow = &xt[tokL][h * 512];
    const float4* gt = gwT4 + h * 128 * 16;
    float4 a4 = make_float4(0.f, 0.f, 0.f, 0.f);
    #pragma unroll 8
    for (int i = 0; i < 128; ++i) {
        float4 xv = *(const float4*)(xrow + 4 * i);  // 4 distinct addrs, bcast
        float4 gv = gt[i * 16 + e];                  // 256B contiguous / 16 lanes
        a4.x = fmaf(xv.x, gv.x, a4.x);
        a4.y = fmaf(xv.y, gv.y, a4.y);
        a4.z = fmaf(xv.z, gv.z, a4.z);
        a4.w = fmaf(xv.w, gv.w, a4.w);
    }
    float acc = (a4.x + a4.y) + (a4.z + a4.w);
    acc += __shfl_xor(acc, 16, 64);                  // merge d-halves
    acc += gate_b[e];

    // ---- C: stable top2 scan in this token's 16 expert lanes ----
    float v0 = -3.0e38f, v1 = -3.0e38f;
    int i0 = 0, i1 = 0;
    const int base = lane & 32;
    #pragma unroll
    for (int j = 0; j < NEXP; ++j) {
        float lv = __shfl(acc, base + j, 64);
        if (lv > v0)      { v1 = v0; i1 = i0; v0 = lv; i0 = j; }
        else if (lv > v1) { v1 = lv; i1 = j; }
    }
    float ex = __expf(v1 - v0);                      // softmax denom cancels
    float w0 = 1.f / (1.f + ex);
    float w1 = ex * w0;

    // hoisted shared-expert column sum for combine slots
    float4 shs[4];
    {
        const float4* s0 = (const float4*)sh;
        const float4* s1 = (const float4*)(sh + DDIM);
        #pragma unroll
        for (int j = 0; j < 4; ++j) {
            float4 p = s0[lane + 64 * j];
            float4 q = s1[lane + 64 * j];
            shs[j] = make_float4(p.x + q.x, p.y + q.y, p.z + q.z, p.w + q.w);
        }
    }

    // ---- D: combine (x from LDS, coalesced out) ----
    #pragma unroll
    for (int tk = 0; tk < 2; ++tk) {
        const int src = tk << 5;
        float a0 = __shfl(w0, src, 64);
        float a1 = __shfl(w1, src, 64);
        int   e0 = __shfl(i0, src, 64);
        int   e1 = __shfl(i1, src, 64);
        const int tokL2 = wave * 2 + tk;
        const float4* xr = (const float4*)&xt[tokL2][0];
        const float4* r0 = (const float4*)(re + (size_t)e0 * DDIM);
        const float4* r1 = (const float4*)(re + (size_t)e1 * DDIM);
        float4* o = (float4*)(out + ((size_t)b * 8 + tokL2) * DDIM);
        #pragma unroll
        for (int j = 0; j < 4; ++j) {
            float4 xv = xr[lane + 64 * j];
            float4 b0 = r0[lane + 64 * j];
            float4 b1 = r1[lane + 64 * j];
            float4 r;
            r.x = xv.x * (shs[j].x + a0 * b0.x + a1 * b1.x);
            r.y = xv.y * (shs[j].y + a0 * b0.y + a1 * b1.y);
            r.z = xv.z * (shs[j].z + a0 * b0.z + a1 * b1.z);
            r.w = xv.w * (shs[j].w + a0 * b0.w + a1 * b1.w);
            o[lane + 64 * j] = r;
        }
    }

    // ---- E1: slot store (agent-scope plain stores) + group ticket ----
    {
        float* slot = ws + WS_SLOT + (size_t)b * DDIM;
        __hip_atomic_store(&slot[4 * t + 0], ss.x, __ATOMIC_RELAXED, __HIP_MEMORY_SCOPE_AGENT);
        __hip_atomic_store(&slot[4 * t + 1], ss.y, __ATOMIC_RELAXED, __HIP_MEMORY_SCOPE_AGENT);
        __hip_atomic_store(&slot[4 * t + 2], ss.z, __ATOMIC_RELAXED, __HIP_MEMORY_SCOPE_AGENT);
        __hip_atomic_store(&slot[4 * t + 3], ss.w, __ATOMIC_RELAXED, __HIP_MEMORY_SCOPE_AGENT);
    }
    __syncthreads();   // vmcnt(0): slot stores globally visible before ticket
    if (t == 0) {
        int a = atomicAdd(&cnt[b >> 4], 1);
        role = (a == GSZ - 1);
    }
    __syncthreads();
    if (!role) return;

    // ---- E2: group reducer (64 parallel blocks, one per contiguous group) ----
    __builtin_amdgcn_fence(__ATOMIC_ACQUIRE, "agent");   // inv only, no wb
    const int grp = b >> 4;
    {
        // 16 contiguous slots = 64 KB span; 16 independent float4 loads/thread
        const float4* sl4 = (const float4*)(ws + WS_SLOT) + (size_t)grp * (GSZ * 256) + t;
        float4 racc = sl4[0];
        #pragma unroll
        for (int k = 1; k < GSZ; ++k) {
            float4 v = sl4[k * 256];
            racc.x += v.x; racc.y += v.y; racc.z += v.z; racc.w += v.w;
        }
        *(float4*)&xt[0][4 * t] = racc;          // sg[4t..4t+3] in LDS (xt dead)
    }
    __syncthreads();

    float gacc = 0.f;
    int pe = 0, pf = 0;
    if (t < NPAIR) {
        int rem = t;
        while (rem >= NEXP - pe) { rem -= NEXP - pe; ++pe; }
        pf = pe + rem;
        const float4* ra = (const float4*)(re + (size_t)pe * DDIM);   // L2-hot
        const float4* rb = (const float4*)(re + (size_t)pf * DDIM);
        const float4* sl = (const float4*)&xt[0][0];                  // bcast reads
        #pragma unroll 8
        for (int i = 0; i < 256; ++i) {
            float4 s = sl[i];
            float4 u = ra[i];
            float4 v = rb[i];
            gacc = fmaf(s.x * u.x, v.x, gacc);
            gacc = fmaf(s.y * u.y, v.y, gacc);
            gacc = fmaf(s.z * u.z, v.z, gacc);
            gacc = fmaf(s.w * u.w, v.w, gacc);
        }
        atomicAdd(ws + WS_G + t, gacc);          // 64 x 136 RMWs total: trivial
    }
    __syncthreads();   // drain G RMWs before fin ticket
    if (t == 0) {
        int f = atomicAdd(&cnt[NGRP], 1);
        role = (f == NGRP - 1);
    }
    __syncthreads();
    if (!role) return;

    // ---- E3: final finisher — loss from complete G (tiny) ----
    __builtin_amdgcn_fence(__ATOMIC_ACQUIRE, "agent");
    float gv = 0.f;
    if (t < NPAIR) gv = (ws + WS_G)[t];
    if (t == 0) lsum = 0.f;
    if (t < NEXP) {
        int idx = t * NEXP - (t * (t - 1)) / 2;  // diagonal (t,t)
        nr[t] = fmaxf(sqrtf((ws + WS_G)[idx]), 1e-8f);
    }
    __syncthreads();
    if (t < NPAIR && pe != pf) {
        float sim = gv / (nr[pe] * nr[pf]);
        sim = fminf(1.f, fmaxf(-1.f, sim));
        atomicAdd(&lsum, 2.f * sim);             // LDS atomic, 120 adds
    }
    __syncthreads();
    if (t == 0)
        out[(size_t)NTOK * DDIM] = lsum / (float)(NEXP * (NEXP - 1)) * 0.1f;
}

extern "C" void kernel_launch(void* const* d_in, const int* in_sizes, int n_in,
                              void* d_out, int out_size, void* d_ws, size_t ws_size,
                              hipStream_t stream) {
    const float* x  = (const float*)d_in[0];
    const float* gw = (const float*)d_in[1];
    const float* gb = (const float*)d_in[2];
    const float* sh = (const float*)d_in[3];
    const float* re = (const float*)d_in[4];
    float* out = (float*)d_out;
    float* ws = (float*)d_ws;   // needs ~4.3 MB (arena 256 MiB)

    moe_prep<<<16, 256, 0, stream>>>(gw, ws);
    moe_fused<<<NBLK, 256, 0, stream>>>(x, gb, sh, re, out, ws);
}

// Round 6
// 129.959 us; speedup vs baseline: 1.6028x; 1.6028x over previous
//
#include <hip/hip_runtime.h>

#define NTOK 8192
#define DDIM 1024
#define NEXP 16
#define NPAIR 136   // E*(E+1)/2 pairs with e<=f
#define XROW 1032   // LDS x-tile row stride in floats (pad 8: 2-way alias only)
#define NBLK 2048   // fused blocks, 4 tokens each
#define NRED 64     // xred_gram blocks, 16-d chunk each

// ws layout (floats): gwT [16384] | slots [2048*1024] = 8 MB | G_part [64*136]
#define WS_GWT  0
#define WS_SLOT 16384
#define WS_GP   (WS_SLOT + NBLK * DDIM)

// ---------------------------------------------------------------------------
// Prep: transpose gate_w [16][1024] -> gwT4[d4][e] (float4 over d, expert-
// contiguous) so routing reads are fully coalesced. Nothing else (no counters
// in this design — ordering comes from dispatch boundaries).
// ---------------------------------------------------------------------------
__global__ __launch_bounds__(256) void moe_prep(
    const float* __restrict__ gate_w,
    float* __restrict__ ws)
{
    const int gid = blockIdx.x * 256 + threadIdx.x;   // 0..4095
    const int e = gid & 15;
    const int d4 = gid >> 4;                          // 0..255
    const float4* gw4 = (const float4*)gate_w;
    float4* gwT4 = (float4*)(ws + WS_GWT);
    gwT4[d4 * 16 + e] = gw4[e * 256 + d4];
}

// ---------------------------------------------------------------------------
// Fused: 2048 blocks x 256 thr, 4 tokens/block (LDS 16.5 KB -> 8 blocks/CU,
// 100% wave occupancy; R4 post-mortem says A-D is latency-bound at 50%).
// A: x-tile -> LDS; thread t owns d-cols 4t..4t+3 -> x^2 partials in regs.
// B: wave = token. lane: e = lane&15, quarter = lane>>4 (256-d each);
//    two shfl_xor merges complete the logit. gwT coalesced, LDS x broadcast.
// C: top2 scan — every lane scans the same ordered 16 values (replicated
//    across quarters), so weights/indices land wave-uniform: no D shuffles.
// D: wave writes its own token, coalesced float4 out, re rows L1/L2-hot.
// E: x^2 partial -> private slot, plain float4 store (no atomics at all;
//    end-of-dispatch release makes it visible to the next kernel).
// ---------------------------------------------------------------------------
__global__ __launch_bounds__(256, 8) void moe_fused(
    const float* __restrict__ x,
    const float* __restrict__ gate_b,
    const float* __restrict__ sh,
    const float* __restrict__ re,
    float* __restrict__ out,
    float* __restrict__ ws)
{
    __shared__ __align__(16) float xt[4][XROW];

    const int t = threadIdx.x;
    const int b = blockIdx.x;
    const float4* gwT4 = (const float4*)(ws + WS_GWT);

    // ---- A: stage 4 token rows, accumulate x^2 for owned d-columns ----
    float4 ss = make_float4(0.f, 0.f, 0.f, 0.f);
    {
        const float4* x4 = (const float4*)x + (size_t)b * 1024;
        #pragma unroll
        for (int i = 0; i < 4; ++i) {
            float4 v = x4[i * 256 + t];
            *(float4*)&xt[i][4 * t] = v;
            ss.x = fmaf(v.x, v.x, ss.x);
            ss.y = fmaf(v.y, v.y, ss.y);
            ss.z = fmaf(v.z, v.z, ss.z);
            ss.w = fmaf(v.w, v.w, ss.w);
        }
    }
    __syncthreads();

    const int lane = t & 63;
    const int wv = t >> 6;          // wave index == local token index
    const int e = lane & 15;
    const int qr = lane >> 4;       // d-quarter 0..3 (256 floats each)

    // ---- B: routing (wave wv computes all 16 logits for token wv) ----
    const float* xrow = &xt[wv][qr * 256];
    const float4* gt = gwT4 + qr * 64 * 16;
    float4 a4 = make_float4(0.f, 0.f, 0.f, 0.f);
    #pragma unroll 8
    for (int i = 0; i < 64; ++i) {
        float4 xv = *(const float4*)(xrow + 4 * i);  // 4 distinct addrs, bcast
        float4 gv = gt[i * 16 + e];                  // 256B contiguous / 16 lanes
        a4.x = fmaf(xv.x, gv.x, a4.x);
        a4.y = fmaf(xv.y, gv.y, a4.y);
        a4.z = fmaf(xv.z, gv.z, a4.z);
        a4.w = fmaf(xv.w, gv.w, a4.w);
    }
    float acc = (a4.x + a4.y) + (a4.z + a4.w);
    acc += __shfl_xor(acc, 16, 64);                  // merge quarter pairs
    acc += __shfl_xor(acc, 32, 64);                  // full 1024-d logit
    acc += gate_b[e];

    // ---- C: stable top2 scan (ascending j, strict > == lax.top_k ties) ----
    float v0 = -3.0e38f, v1 = -3.0e38f;
    int i0 = 0, i1 = 0;
    const int base = lane & 48;                      // stay in own quarter
    #pragma unroll
    for (int j = 0; j < NEXP; ++j) {
        float lv = __shfl(acc, base + j, 64);
        if (lv > v0)      { v1 = v0; i1 = i0; v0 = lv; i0 = j; }
        else if (lv > v1) { v1 = lv; i1 = j; }
    }
    float ex = __expf(v1 - v0);                      // softmax denom cancels
    float w0 = 1.f / (1.f + ex);
    float w1 = ex * w0;
    // (v0,i0,v1,i1) identical across the wave: no shuffles needed in D.

    // hoisted shared-expert column sum for combine slots
    float4 shs[4];
    {
        const float4* s0 = (const float4*)sh;
        const float4* s1 = (const float4*)(sh + DDIM);
        #pragma unroll
        for (int j = 0; j < 4; ++j) {
            float4 p = s0[lane + 64 * j];
            float4 s = s1[lane + 64 * j];
            shs[j] = make_float4(p.x + s.x, p.y + s.y, p.z + s.z, p.w + s.w);
        }
    }

    // ---- D: combine — wave wv writes token wv ----
    {
        const float4* xr = (const float4*)&xt[wv][0];
        const float4* r0 = (const float4*)(re + (size_t)i0 * DDIM);
        const float4* r1 = (const float4*)(re + (size_t)i1 * DDIM);
        float4* o = (float4*)(out + ((size_t)b * 4 + wv) * DDIM);
        #pragma unroll
        for (int j = 0; j < 4; ++j) {
            const int idx = lane + 64 * j;
            float4 xv = xr[idx];
            float4 b0 = r0[idx];
            float4 b1 = r1[idx];
            float4 r;
            r.x = xv.x * (shs[j].x + w0 * b0.x + w1 * b1.x);
            r.y = xv.y * (shs[j].y + w0 * b0.y + w1 * b1.y);
            r.z = xv.z * (shs[j].z + w0 * b0.z + w1 * b1.z);
            r.w = xv.w * (shs[j].w + w0 * b0.w + w1 * b1.w);
            o[idx] = r;
        }
    }

    // ---- E: x^2 partial -> private slot (plain coalesced store) ----
    *(float4*)(ws + WS_SLOT + (size_t)b * DDIM + 4 * t) = ss;
}

// ---------------------------------------------------------------------------
// xred_gram: 64 blocks x 256 thr. Block j owns d-chunk [16j, 16j+16).
// 1) Reduce 2048 slots for the chunk (32 strided float4 loads/thread, 8 MB
//    total across 64 parallel blocks).  2) LDS tree to s_loc[16].
// 3) Stage reT[16][16] (chunk of re, transposed).  4) 136 pair-threads do a
//    16-iter LDS-only partial Gram -> G_part[j][p].  (R0's proven pattern:
//    massively parallel, no global-latency serial loops.)
// ---------------------------------------------------------------------------
__global__ __launch_bounds__(256) void moe_xred_gram(
    const float* __restrict__ re,
    float* __restrict__ ws)
{
    __shared__ float4 s4[64][4];
    __shared__ float s_loc[16];
    __shared__ float reT[16][16];   // [dd][e]

    const int t = threadIdx.x;
    const int j = blockIdx.x;       // d-chunk index
    const int c = t & 3;            // float4 col within chunk
    const int r = t >> 2;           // 0..63

    // 1) slot reduction: thread (c,r) sums slots b2 = r + 64k, k=0..31
    {
        const float4* sl4 = (const float4*)(ws + WS_SLOT);
        const size_t colbase = (size_t)4 * j + c;
        float4 acc = make_float4(0.f, 0.f, 0.f, 0.f);
        #pragma unroll 8
        for (int k = 0; k < 32; ++k) {
            float4 v = sl4[(size_t)(r + 64 * k) * 256 + colbase];
            acc.x += v.x; acc.y += v.y; acc.z += v.z; acc.w += v.w;
        }
        s4[r][c] = acc;
    }
    // 3) stage reT chunk (all 256 threads: e = t>>4, dd = t&15)
    {
        const int e = t >> 4, dd = t & 15;
        reT[dd][e] = re[(size_t)e * DDIM + 16 * j + dd];
    }
    __syncthreads();

    // 2) finish chunk reduction: 4 threads fold 64 partials each
    if (t < 4) {
        float4 a = s4[0][t];
        for (int rr = 1; rr < 64; ++rr) {
            float4 v = s4[rr][t];
            a.x += v.x; a.y += v.y; a.z += v.z; a.w += v.w;
        }
        s_loc[4 * t + 0] = a.x;
        s_loc[4 * t + 1] = a.y;
        s_loc[4 * t + 2] = a.z;
        s_loc[4 * t + 3] = a.w;
    }
    __syncthreads();

    // 4) partial Gram over this 16-d chunk (LDS-only, conflict-free bcast)
    if (t < NPAIR) {
        int pe = 0, rem = t;
        while (rem >= NEXP - pe) { rem -= NEXP - pe; ++pe; }
        const int pf = pe + rem;
        float a = 0.f;
        #pragma unroll
        for (int dd = 0; dd < 16; ++dd)
            a += s_loc[dd] * reT[dd][pe] * reT[dd][pf];
        (ws + WS_GP)[j * NPAIR + t] = a;
    }
}

// ---------------------------------------------------------------------------
// Final: sum 64 partial Grams, norms from diagonal, clipped cosine mean.
// ---------------------------------------------------------------------------
__global__ __launch_bounds__(192) void moe_final(
    const float* __restrict__ ws,
    float* __restrict__ div_out)
{
    __shared__ float G[NPAIR];
    __shared__ float nr[NEXP];
    __shared__ float lsum;
    const int t = threadIdx.x;

    if (t == 0) lsum = 0.f;
    if (t < NPAIR) {
        const float* gp = ws + WS_GP;
        float g = 0.f;
        #pragma unroll 8
        for (int jj = 0; jj < NRED; ++jj) g += gp[jj * NPAIR + t];
        G[t] = g;
    }
    __syncthreads();
    if (t < NEXP) {
        int idx = t * NEXP - (t * (t - 1)) / 2;   // diagonal (t,t)
        nr[t] = fmaxf(sqrtf(G[idx]), 1e-8f);
    }
    __syncthreads();
    if (t < NPAIR) {
        int pe = 0, rem = t;
        while (rem >= NEXP - pe) { rem -= NEXP - pe; ++pe; }
        const int pf = pe + rem;
        if (pe != pf) {
            float sim = G[t] / (nr[pe] * nr[pf]);
            sim = fminf(1.f, fmaxf(-1.f, sim));
            atomicAdd(&lsum, 2.f * sim);
        }
    }
    __syncthreads();
    if (t == 0) *div_out = lsum / (float)(NEXP * (NEXP - 1)) * 0.1f;
}

extern "C" void kernel_launch(void* const* d_in, const int* in_sizes, int n_in,
                              void* d_out, int out_size, void* d_ws, size_t ws_size,
                              hipStream_t stream) {
    const float* x  = (const float*)d_in[0];
    const float* gw = (const float*)d_in[1];
    const float* gb = (const float*)d_in[2];
    const float* sh = (const float*)d_in[3];
    const float* re = (const float*)d_in[4];
    float* out = (float*)d_out;
    float* ws = (float*)d_ws;   // needs ~8.5 MB (arena 256 MiB)

    moe_prep<<<16, 256, 0, stream>>>(gw, ws);
    moe_fused<<<NBLK, 256, 0, stream>>>(x, gb, sh, re, out, ws);
    moe_xred_gram<<<NRED, 256, 0, stream>>>(re, ws);
    moe_final<<<1, 192, 0, stream>>>(ws, out + (size_t)NTOK * DDIM);
}